// Round 1
// 24144.453 us; speedup vs baseline: 1.3141x; 1.3141x over previous
//
#include <hip/hip_runtime.h>
#include <cmath>

// Problem constants: B=256, T=512, D=1024, U=1024; M = B*T = 131072.
#define BN 256
#define TN 512
#define DN 1024
#define UN 1024
#define STEPS_P1 (TN + 1)

typedef _Float16 half8 __attribute__((ext_vector_type(8)));
typedef _Float16 half4v __attribute__((ext_vector_type(4)));
typedef float floatx4 __attribute__((ext_vector_type(4)));

// ---------------------------------------------------------------------------
// Phase 1: build WcT[n][k] = (kernel[k][n] * u_cur[k][n]) and
//          WpT[n][k] = (rkernel[k][n] * u_prev[k][n]) as f16, transposed.
// ---------------------------------------------------------------------------
__global__ __launch_bounds__(256) void prep_weights(
    const float* __restrict__ kernel,   // [D][U]
    const float* __restrict__ rkernel,  // [U][U]
    const float* __restrict__ mu_c, const float* __restrict__ si_c,
    const float* __restrict__ mu_p, const float* __restrict__ si_p,
    _Float16* __restrict__ WcT,         // [U][D]
    _Float16* __restrict__ WpT)         // [U][U]
{
    __shared__ float g[1024];
    __shared__ float red[256];
    const int j = blockIdx.x;
    const bool prev = (blockIdx.y == 1);
    const float* K = prev ? rkernel : kernel;
    float mu = prev ? mu_p[j] : mu_c[j];
    float si = prev ? si_p[j] : si_c[j];
    si = fminf(fmaxf(si, 0.01f), 1.0f);
    const float inv2s2 = 1.0f / (2.0f * si * si);
    const float step = 1.0f / 1023.0f;

    float ss = 0.0f;
#pragma unroll
    for (int s = 0; s < 4; ++s) {
        int i = threadIdx.x + s * 256;
        float d = (float)i * step - mu;
        float v = expf(-d * d * inv2s2);
        g[i] = v;
        ss += v * v;
    }
    red[threadIdx.x] = ss;
    __syncthreads();
    for (int off = 128; off > 0; off >>= 1) {
        if (threadIdx.x < (unsigned)off) red[threadIdx.x] += red[threadIdx.x + off];
        __syncthreads();
    }
    const float scale = 32.0f * rsqrtf(red[0]);
    _Float16* dst = prev ? WpT : WcT;
#pragma unroll
    for (int s = 0; s < 4; ++s) {
        int i = threadIdx.x + s * 256;
        dst[(long)j * 1024 + i] = (_Float16)(K[(long)i * 1024 + j] * g[i] * scale);
    }
}

// ---------------------------------------------------------------------------
// Phase 2: Z = X @ Wc  (written into d_out).  Unchanged from verified kernel.
// ---------------------------------------------------------------------------
__global__ __launch_bounds__(512, 2) void gemm_z(
    const float* __restrict__ X,        // [M][1024]
    const _Float16* __restrict__ WcT,   // [1024][1024]  (n-major)
    const float* __restrict__ bias,     // [1024]
    float* __restrict__ Z)              // [M][1024]  == d_out
{
    __shared__ _Float16 lA[64 * 40];    // 64 rows, stride 40 (pad 8)

    const int tid  = threadIdx.x;
    const int wave = tid >> 6;
    const int lane = tid & 63;
    const int q    = lane >> 4;         // 0..3
    const int ln   = lane & 15;         // 0..15
    const int ncol0 = wave * 128;
    const long m_base = (long)blockIdx.x * 64;

    const int arow = tid >> 3;          // 0..63
    const int acq  = tid & 7;           // 0..7  (each covers 4 k)

    floatx4 acc[4][8];
#pragma unroll
    for (int ms = 0; ms < 4; ++ms)
#pragma unroll
        for (int ns = 0; ns < 8; ++ns) acc[ms][ns] = (floatx4){0.f, 0.f, 0.f, 0.f};

    for (int k0 = 0; k0 < 1024; k0 += 32) {
        float4 v = *(const float4*)(X + (m_base + arow) * 1024 + k0 + acq * 4);
        half4v hv = { (_Float16)v.x, (_Float16)v.y, (_Float16)v.z, (_Float16)v.w };
        *(half4v*)(&lA[arow * 40 + acq * 4]) = hv;
        __syncthreads();

        half8 a[4];
#pragma unroll
        for (int ms = 0; ms < 4; ++ms)
            a[ms] = *(const half8*)(&lA[(ms * 16 + ln) * 40 + q * 8]);

#pragma unroll
        for (int ns = 0; ns < 8; ++ns) {
            half8 b = *(const half8*)(WcT + (long)(ncol0 + ns * 16 + ln) * 1024 + k0 + q * 8);
#pragma unroll
            for (int ms = 0; ms < 4; ++ms)
                acc[ms][ns] = __builtin_amdgcn_mfma_f32_16x16x32_f16(a[ms], b, acc[ms][ns], 0, 0, 0);
        }
        __syncthreads();
    }

#pragma unroll
    for (int ns = 0; ns < 8; ++ns) {
        int col = ncol0 + ns * 16 + ln;
        float bs = bias[col];
#pragma unroll
        for (int ms = 0; ms < 4; ++ms) {
#pragma unroll
            for (int r = 0; r < 4; ++r) {
                long row = m_base + ms * 16 + q * 4 + r;
                Z[row * 1024 + col] = acc[ms][ns][r] + bs;
            }
        }
    }
}

// ---------------------------------------------------------------------------
// Phase 3: cooperative 2-D-decomposed recurrence.
// Grid = 256 blocks (16 batch-groups x 16 col-groups), 256 threads each.
// Block (bi,nj): rows [bi*16,+16), cols [nj*64,+64).  Wave w owns 16 cols.
// h exchanged via double-buffered global f16 hbuf; per-step per-group
// barrier over fresh counters (16 arrivals), agent-scope fences for
// cross-XCD visibility (G16).
// ---------------------------------------------------------------------------
__device__ __forceinline__ float fast_tanh(float x) {
    return 1.0f - 2.0f / (__expf(2.0f * x) + 1.0f);
}

__global__ __launch_bounds__(256, 1) void rnn_scan(
    const _Float16* __restrict__ WpT,   // [1024][1024] (n-major), L2-resident
    float* __restrict__ Zout,           // [B][T][U], Z in, h out (in place)
    _Float16* __restrict__ hbuf,        // [2][256][1024] f16
    unsigned* __restrict__ cnt)         // [16][TN+1], pre-zeroed
{
    __shared__ _Float16 hs[16 * 1032];  // h_{t-1} rows, padded stride (33 KB)

    const int tid  = threadIdx.x;
    const int wave = tid >> 6;
    const int lane = tid & 63;
    const int q    = lane >> 4;         // 0..3
    const int ln   = lane & 15;         // 0..15
    const int bi   = blockIdx.x >> 4;   // batch group (consecutive blocks = one group)
    const int nj   = blockIdx.x & 15;   // col group
    const int col  = nj * 64 + wave * 16 + ln;

    unsigned* mycnt = cnt + bi * STEPS_P1;

    // ---- init: zero own slice of hbuf[0] (h_{-1} = 0), then arrive ----
    {
        int r = tid >> 4;               // 0..15
        int c = (tid & 15) * 4;         // 0..60
        *(unsigned long long*)(hbuf + (long)(bi * 16 + r) * 1024 + nj * 64 + c) = 0ull;
    }
    __threadfence();
    __syncthreads();
    if (tid == 0)
        __hip_atomic_fetch_add(&mycnt[0], 1u, __ATOMIC_RELEASE, __HIP_MEMORY_SCOPE_AGENT);

    const _Float16* bp = WpT + (long)col * 1024 + q * 8;   // this lane's B row

    for (int t = 0; t < TN; ++t) {
        // ---- wait until all 16 blocks of this batch group published h_{t-1} ----
        if (tid == 0) {
            while (__hip_atomic_load(&mycnt[t], __ATOMIC_RELAXED, __HIP_MEMORY_SCOPE_AGENT) < 16u)
                __builtin_amdgcn_s_sleep(1);
            __builtin_amdgcn_fence(__ATOMIC_ACQUIRE, "agent");  // inv L1/L2
        }
        __syncthreads();

        // ---- stage h_{t-1} (16 rows x 1024 f16 = 32 KB) into LDS ----
        const _Float16* hp = hbuf + (long)(t & 1) * (BN * UN) + (long)bi * 16 * 1024;
#pragma unroll
        for (int i = 0; i < 8; ++i) {
            int d   = i * 256 + tid;    // 0..2047 16B-chunks
            int row = d >> 7;           // 0..15
            int ce  = (d & 127) * 8;    // f16 offset in row
            *(float4*)(hs + row * 1032 + ce) = *(const float4*)(hp + row * 1024 + ce);
        }

        // ---- prefetch Z slice for this step (hides HBM latency under MFMA) ----
        const long zbase = ((long)(bi * 16 + q * 4) * TN + t) * 1024 + col;
        float z0 = Zout[zbase];
        float z1 = Zout[zbase + (long)TN * 1024];
        float z2 = Zout[zbase + 2L * TN * 1024];
        float z3 = Zout[zbase + 3L * TN * 1024];
        __syncthreads();

        // ---- h_{t-1} @ Wp slice: 32 k-iters, 4 independent MFMA chains ----
        floatx4 acc[4];
#pragma unroll
        for (int c4 = 0; c4 < 4; ++c4) acc[c4] = (floatx4){0.f, 0.f, 0.f, 0.f};
#pragma unroll
        for (int kk = 0; kk < 32; ++kk) {
            half8 a = *(const half8*)(hs + ln * 1032 + kk * 32 + q * 8);
            half8 b = *(const half8*)(bp + kk * 32);
            acc[kk & 3] = __builtin_amdgcn_mfma_f32_16x16x32_f16(a, b, acc[kk & 3], 0, 0, 0);
        }
        floatx4 s = (acc[0] + acc[1]) + (acc[2] + acc[3]);

        // ---- epilogue: tanh, write out (in place) + publish h_t slice ----
        _Float16* hnext = hbuf + (long)((t + 1) & 1) * (BN * UN)
                        + (long)(bi * 16 + q * 4) * 1024 + col;
        float zv0 = fast_tanh(z0 + s[0]);
        float zv1 = fast_tanh(z1 + s[1]);
        float zv2 = fast_tanh(z2 + s[2]);
        float zv3 = fast_tanh(z3 + s[3]);
        Zout[zbase]                    = zv0;
        Zout[zbase + (long)TN * 1024]  = zv1;
        Zout[zbase + 2L * TN * 1024]   = zv2;
        Zout[zbase + 3L * TN * 1024]   = zv3;
        hnext[0]        = (_Float16)zv0;
        hnext[1024]     = (_Float16)zv1;
        hnext[2 * 1024] = (_Float16)zv2;
        hnext[3 * 1024] = (_Float16)zv3;

        __threadfence();                 // wbL2: make stores agent-visible
        __syncthreads();                 // all threads' fences done
        if (tid == 0)
            __hip_atomic_fetch_add(&mycnt[t + 1], 1u, __ATOMIC_RELEASE, __HIP_MEMORY_SCOPE_AGENT);
    }
}

// ---------------------------------------------------------------------------
extern "C" void kernel_launch(void* const* d_in, const int* in_sizes, int n_in,
                              void* d_out, int out_size, void* d_ws, size_t ws_size,
                              hipStream_t stream) {
    (void)in_sizes; (void)n_in; (void)out_size; (void)ws_size;
    const float* X    = (const float*)d_in[0];
    // d_in[1] = h0 (zeros, folded into hbuf init)
    const float* K    = (const float*)d_in[2];
    const float* RK   = (const float*)d_in[3];
    const float* bias = (const float*)d_in[4];
    const float* muc  = (const float*)d_in[5];
    const float* sic  = (const float*)d_in[6];
    const float* mup  = (const float*)d_in[7];
    const float* sip  = (const float*)d_in[8];
    float* out = (float*)d_out;

    // Workspace layout (4 MiB total, unchanged footprint):
    //   [0, 2 MiB)   WcT  (dead after gemm_z) — reused by rnn_scan as:
    //                [0, 1 MiB)        hbuf  (2 x 256 x 1024 f16)
    //                [1 MiB, +32 KB)   barrier counters
    //   [2 MiB, 4 MiB) WpT
    _Float16* WcT  = (_Float16*)d_ws;
    _Float16* WpT  = WcT + 1024 * 1024;
    _Float16* hbuf = (_Float16*)d_ws;
    unsigned* cnt  = (unsigned*)((char*)d_ws + (1u << 20));

    prep_weights<<<dim3(1024, 2), 256, 0, stream>>>(K, RK, muc, sic, mup, sip, WcT, WpT);
    gemm_z<<<dim3((BN * TN) / 64), 512, 0, stream>>>(X, WcT, bias, out);

    // zero the per-step barrier counters (after gemm_z — region aliases WcT)
    hipMemsetAsync(cnt, 0, 16 * STEPS_P1 * sizeof(unsigned), stream);

    const _Float16* WpT_c = WpT;
    float* out_p = out;
    _Float16* hbuf_p = hbuf;
    unsigned* cnt_p = cnt;
    void* kargs[] = { (void*)&WpT_c, (void*)&out_p, (void*)&hbuf_p, (void*)&cnt_p };
    hipLaunchCooperativeKernel((const void*)rnn_scan, dim3(16 * 16), dim3(256),
                               kargs, 0, stream);
}

// Round 2
// 3199.900 us; speedup vs baseline: 9.9151x; 7.5454x over previous
//
#include <hip/hip_runtime.h>
#include <cmath>

// Problem constants: B=256, T=512, D=1024, U=1024; M = B*T = 131072.
#define BN 256
#define TN 512
#define DN 1024
#define UN 1024
#define STEPS_P1 (TN + 1)

typedef _Float16 half8 __attribute__((ext_vector_type(8)));
typedef _Float16 half4v __attribute__((ext_vector_type(4)));
typedef float floatx4 __attribute__((ext_vector_type(4)));

// ---------------------------------------------------------------------------
// Phase 1: build WcT[n][k] = (kernel[k][n] * u_cur[k][n]) and
//          WpT[n][k] = (rkernel[k][n] * u_prev[k][n]) as f16, transposed.
// ---------------------------------------------------------------------------
__global__ __launch_bounds__(256) void prep_weights(
    const float* __restrict__ kernel,   // [D][U]
    const float* __restrict__ rkernel,  // [U][U]
    const float* __restrict__ mu_c, const float* __restrict__ si_c,
    const float* __restrict__ mu_p, const float* __restrict__ si_p,
    _Float16* __restrict__ WcT,         // [U][D]
    _Float16* __restrict__ WpT)         // [U][U]
{
    __shared__ float g[1024];
    __shared__ float red[256];
    const int j = blockIdx.x;
    const bool prev = (blockIdx.y == 1);
    const float* K = prev ? rkernel : kernel;
    float mu = prev ? mu_p[j] : mu_c[j];
    float si = prev ? si_p[j] : si_c[j];
    si = fminf(fmaxf(si, 0.01f), 1.0f);
    const float inv2s2 = 1.0f / (2.0f * si * si);
    const float step = 1.0f / 1023.0f;

    float ss = 0.0f;
#pragma unroll
    for (int s = 0; s < 4; ++s) {
        int i = threadIdx.x + s * 256;
        float d = (float)i * step - mu;
        float v = expf(-d * d * inv2s2);
        g[i] = v;
        ss += v * v;
    }
    red[threadIdx.x] = ss;
    __syncthreads();
    for (int off = 128; off > 0; off >>= 1) {
        if (threadIdx.x < (unsigned)off) red[threadIdx.x] += red[threadIdx.x + off];
        __syncthreads();
    }
    const float scale = 32.0f * rsqrtf(red[0]);
    _Float16* dst = prev ? WpT : WcT;
#pragma unroll
    for (int s = 0; s < 4; ++s) {
        int i = threadIdx.x + s * 256;
        dst[(long)j * 1024 + i] = (_Float16)(K[(long)i * 1024 + j] * g[i] * scale);
    }
}

// ---------------------------------------------------------------------------
// Phase 2: Z = X @ Wc  (written into d_out).  Unchanged from verified kernel.
// ---------------------------------------------------------------------------
__global__ __launch_bounds__(512, 2) void gemm_z(
    const float* __restrict__ X,        // [M][1024]
    const _Float16* __restrict__ WcT,   // [1024][1024]  (n-major)
    const float* __restrict__ bias,     // [1024]
    float* __restrict__ Z)              // [M][1024]  == d_out
{
    __shared__ _Float16 lA[64 * 40];    // 64 rows, stride 40 (pad 8)

    const int tid  = threadIdx.x;
    const int wave = tid >> 6;
    const int lane = tid & 63;
    const int q    = lane >> 4;         // 0..3
    const int ln   = lane & 15;         // 0..15
    const int ncol0 = wave * 128;
    const long m_base = (long)blockIdx.x * 64;

    const int arow = tid >> 3;          // 0..63
    const int acq  = tid & 7;           // 0..7  (each covers 4 k)

    floatx4 acc[4][8];
#pragma unroll
    for (int ms = 0; ms < 4; ++ms)
#pragma unroll
        for (int ns = 0; ns < 8; ++ns) acc[ms][ns] = (floatx4){0.f, 0.f, 0.f, 0.f};

    for (int k0 = 0; k0 < 1024; k0 += 32) {
        float4 v = *(const float4*)(X + (m_base + arow) * 1024 + k0 + acq * 4);
        half4v hv = { (_Float16)v.x, (_Float16)v.y, (_Float16)v.z, (_Float16)v.w };
        *(half4v*)(&lA[arow * 40 + acq * 4]) = hv;
        __syncthreads();

        half8 a[4];
#pragma unroll
        for (int ms = 0; ms < 4; ++ms)
            a[ms] = *(const half8*)(&lA[(ms * 16 + ln) * 40 + q * 8]);

#pragma unroll
        for (int ns = 0; ns < 8; ++ns) {
            half8 b = *(const half8*)(WcT + (long)(ncol0 + ns * 16 + ln) * 1024 + k0 + q * 8);
#pragma unroll
            for (int ms = 0; ms < 4; ++ms)
                acc[ms][ns] = __builtin_amdgcn_mfma_f32_16x16x32_f16(a[ms], b, acc[ms][ns], 0, 0, 0);
        }
        __syncthreads();
    }

#pragma unroll
    for (int ns = 0; ns < 8; ++ns) {
        int col = ncol0 + ns * 16 + ln;
        float bs = bias[col];
#pragma unroll
        for (int ms = 0; ms < 4; ++ms) {
#pragma unroll
            for (int r = 0; r < 4; ++r) {
                long row = m_base + ms * 16 + q * 4 + r;
                Z[row * 1024 + col] = acc[ms][ns][r] + bs;
            }
        }
    }
}

// ---------------------------------------------------------------------------
// Phase 3: cooperative 2-D recurrence, FENCE-FREE handshake.
// Grid = 256 blocks (16 batch-groups x 16 col-groups), 256 threads each.
// - Wp slice lives in VGPRs (32x half8/lane), loaded once: zero per-step
//   WpT traffic, and no agent fences means L2 stays hot for Z.
// - h exchange through hbuf with RELAXED/AGENT atomics (write-through to
//   the coherence point): data ops themselves are coherent, so no
//   buffer_wbl2 / buffer_inv per step.  Release ordering = per-thread
//   s_waitcnt vmcnt(0) + __syncthreads before the counter add; acquire =
//   poll + barrier (+ cheap workgroup fence for compiler ordering).
// - MFMA operands SWAPPED vs gemm_z: D = Wp_frag x h_frag, so each lane
//   holds (batch row = ln, 4 consecutive cols = q*4+r) -> float4 Z I/O and
//   one aligned 8-byte h publish per lane.
// ---------------------------------------------------------------------------
__device__ __forceinline__ float fast_tanh(float x) {
    return 1.0f - 2.0f / (__expf(2.0f * x) + 1.0f);
}

__global__ __launch_bounds__(256, 1) void rnn_scan(
    const _Float16* __restrict__ WpT,   // [1024][1024] (n-major)
    float* __restrict__ Zout,           // [B][T][U], Z in, h out (in place)
    _Float16* __restrict__ hbuf,        // [2][256][1024] f16
    unsigned* __restrict__ cnt)         // [16][TN+1], pre-zeroed
{
    __shared__ _Float16 hs[16 * 1032];  // h_{t-1}, padded stride

    const int tid  = threadIdx.x;
    const int wave = tid >> 6;
    const int lane = tid & 63;
    const int q    = lane >> 4;         // 0..3
    const int ln   = lane & 15;         // 0..15
    const int bi   = blockIdx.x >> 4;   // batch group
    const int nj   = blockIdx.x & 15;   // col group
    const int ncol0 = nj * 64 + wave * 16;   // this wave's 16-col base
    const int hrow  = bi * 16 + ln;          // this lane's batch row

    unsigned* mycnt = cnt + bi * STEPS_P1;

    // ---- preload Wp slice into registers: cols [ncol0, ncol0+16) ----
    half8 b[32];
    {
        const _Float16* bp = WpT + (long)(ncol0 + ln) * 1024 + q * 8;
#pragma unroll
        for (int kk = 0; kk < 32; ++kk) b[kk] = *(const half8*)(bp + kk * 32);
    }

    // ---- init: zero own hbuf[0] slice (h_{-1}=0) via bypass stores ----
    {
        unsigned long long* p = (unsigned long long*)
            (hbuf + (long)(bi * 16 + (tid >> 4)) * 1024 + nj * 64 + (tid & 15) * 4);
        __hip_atomic_store(p, 0ull, __ATOMIC_RELAXED, __HIP_MEMORY_SCOPE_AGENT);
    }
    asm volatile("s_waitcnt vmcnt(0)" ::: "memory");
    __syncthreads();
    if (tid == 0)
        __hip_atomic_fetch_add(&mycnt[0], 1u, __ATOMIC_RELAXED, __HIP_MEMORY_SCOPE_AGENT);

    for (int t = 0; t < TN; ++t) {
        // ---- Z prefetch for this step (before the wait -> latency hidden) ----
        const long zoff = ((long)hrow * TN + t) * 1024 + ncol0 + q * 4;
        float4 z = *(const float4*)(Zout + zoff);

        // ---- wait: all 16 blocks of this group published h_{t-1} ----
        if (tid == 0) {
            while (__hip_atomic_load(&mycnt[t], __ATOMIC_RELAXED, __HIP_MEMORY_SCOPE_AGENT) < 16u)
                __builtin_amdgcn_s_sleep(1);
        }
        __syncthreads();
        __builtin_amdgcn_fence(__ATOMIC_ACQUIRE, "workgroup");  // compiler ordering; no cache inv

        // ---- stage h_{t-1} (32 KB) into LDS via coherence-point loads ----
        const unsigned long long* hp = (const unsigned long long*)
            (hbuf + (long)(t & 1) * (BN * UN) + (long)bi * 16 * 1024);
        unsigned long long tmp[16];
#pragma unroll
        for (int i = 0; i < 16; ++i)
            tmp[i] = __hip_atomic_load(hp + i * 256 + tid, __ATOMIC_RELAXED, __HIP_MEMORY_SCOPE_AGENT);
#pragma unroll
        for (int i = 0; i < 16; ++i) {
            int d   = i * 256 + tid;
            int row = d >> 8;           // 0..15
            int c8  = d & 255;          // 8B-chunk within row
            *(unsigned long long*)(hs + row * 1032 + c8 * 4) = tmp[i];
        }
        __syncthreads();

        // ---- (Wp slice)^T x h : 32 k-iters, b from regs, a from LDS ----
        floatx4 acc[4];
#pragma unroll
        for (int c4 = 0; c4 < 4; ++c4) acc[c4] = (floatx4){0.f, 0.f, 0.f, 0.f};
#pragma unroll
        for (int kk = 0; kk < 32; ++kk) {
            half8 a = *(const half8*)(hs + ln * 1032 + kk * 32 + q * 8);
            acc[kk & 3] = __builtin_amdgcn_mfma_f32_16x16x32_f16(b[kk], a, acc[kk & 3], 0, 0, 0);
        }
        floatx4 s = (acc[0] + acc[1]) + (acc[2] + acc[3]);

        // ---- epilogue: tanh, float4 Z write, 8B h publish ----
        float4 hv;
        hv.x = fast_tanh(z.x + s[0]);
        hv.y = fast_tanh(z.y + s[1]);
        hv.z = fast_tanh(z.z + s[2]);
        hv.w = fast_tanh(z.w + s[3]);
        *(float4*)(Zout + zoff) = hv;

        union { _Float16 h[4]; unsigned long long u; } pk;
        pk.h[0] = (_Float16)hv.x; pk.h[1] = (_Float16)hv.y;
        pk.h[2] = (_Float16)hv.z; pk.h[3] = (_Float16)hv.w;
        unsigned long long* hn = (unsigned long long*)
            (hbuf + (long)((t + 1) & 1) * (BN * UN) + (long)hrow * 1024 + ncol0 + q * 4);
        __hip_atomic_store(hn, pk.u, __ATOMIC_RELAXED, __HIP_MEMORY_SCOPE_AGENT);

        // ---- release: own stores acked at coherence point, then signal ----
        asm volatile("s_waitcnt vmcnt(0)" ::: "memory");
        __syncthreads();
        if (tid == 0)
            __hip_atomic_fetch_add(&mycnt[t + 1], 1u, __ATOMIC_RELAXED, __HIP_MEMORY_SCOPE_AGENT);
    }
}

// ---------------------------------------------------------------------------
extern "C" void kernel_launch(void* const* d_in, const int* in_sizes, int n_in,
                              void* d_out, int out_size, void* d_ws, size_t ws_size,
                              hipStream_t stream) {
    (void)in_sizes; (void)n_in; (void)out_size; (void)ws_size;
    const float* X    = (const float*)d_in[0];
    // d_in[1] = h0 (zeros, folded into hbuf init)
    const float* K    = (const float*)d_in[2];
    const float* RK   = (const float*)d_in[3];
    const float* bias = (const float*)d_in[4];
    const float* muc  = (const float*)d_in[5];
    const float* sic  = (const float*)d_in[6];
    const float* mup  = (const float*)d_in[7];
    const float* sip  = (const float*)d_in[8];
    float* out = (float*)d_out;

    // Workspace layout (4 MiB):
    //   [0, 2 MiB)   WcT  (dead after gemm_z) — reused by rnn_scan as:
    //                [0, 1 MiB)        hbuf  (2 x 256 x 1024 f16)
    //                [1 MiB, +32.1 KB) barrier counters
    //   [2 MiB, 4 MiB) WpT
    _Float16* WcT  = (_Float16*)d_ws;
    _Float16* WpT  = WcT + 1024 * 1024;
    _Float16* hbuf = (_Float16*)d_ws;
    unsigned* cnt  = (unsigned*)((char*)d_ws + (1u << 20));

    prep_weights<<<dim3(1024, 2), 256, 0, stream>>>(K, RK, muc, sic, mup, sip, WcT, WpT);
    gemm_z<<<dim3((BN * TN) / 64), 512, 0, stream>>>(X, WcT, bias, out);

    // zero the per-step barrier counters (after gemm_z — region aliases WcT)
    hipMemsetAsync(cnt, 0, 16 * STEPS_P1 * sizeof(unsigned), stream);

    const _Float16* WpT_c = WpT;
    float* out_p = out;
    _Float16* hbuf_p = hbuf;
    unsigned* cnt_p = cnt;
    void* kargs[] = { (void*)&WpT_c, (void*)&out_p, (void*)&hbuf_p, (void*)&cnt_p };
    hipLaunchCooperativeKernel((const void*)rnn_scan, dim3(16 * 16), dim3(256),
                               kargs, 0, stream);
}

// Round 3
// 3084.183 us; speedup vs baseline: 10.2872x; 1.0375x over previous
//
#include <hip/hip_runtime.h>
#include <cmath>

// Problem constants: B=256, T=512, D=1024, U=1024; M = B*T = 131072.
#define BN 256
#define TN 512
#define DN 1024
#define UN 1024
#define STEPS_P1 (TN + 1)

typedef _Float16 half8 __attribute__((ext_vector_type(8)));
typedef _Float16 half4v __attribute__((ext_vector_type(4)));
typedef float floatx4 __attribute__((ext_vector_type(4)));

// ---------------------------------------------------------------------------
// Phase 1: build WcT[n][k] = (kernel[k][n] * u_cur[k][n]) and
//          WpT[n][k] = (rkernel[k][n] * u_prev[k][n]) as f16, transposed.
// ---------------------------------------------------------------------------
__global__ __launch_bounds__(256) void prep_weights(
    const float* __restrict__ kernel,   // [D][U]
    const float* __restrict__ rkernel,  // [U][U]
    const float* __restrict__ mu_c, const float* __restrict__ si_c,
    const float* __restrict__ mu_p, const float* __restrict__ si_p,
    _Float16* __restrict__ WcT,         // [U][D]
    _Float16* __restrict__ WpT)         // [U][U]
{
    __shared__ float g[1024];
    __shared__ float red[256];
    const int j = blockIdx.x;
    const bool prev = (blockIdx.y == 1);
    const float* K = prev ? rkernel : kernel;
    float mu = prev ? mu_p[j] : mu_c[j];
    float si = prev ? si_p[j] : si_c[j];
    si = fminf(fmaxf(si, 0.01f), 1.0f);
    const float inv2s2 = 1.0f / (2.0f * si * si);
    const float step = 1.0f / 1023.0f;

    float ss = 0.0f;
#pragma unroll
    for (int s = 0; s < 4; ++s) {
        int i = threadIdx.x + s * 256;
        float d = (float)i * step - mu;
        float v = expf(-d * d * inv2s2);
        g[i] = v;
        ss += v * v;
    }
    red[threadIdx.x] = ss;
    __syncthreads();
    for (int off = 128; off > 0; off >>= 1) {
        if (threadIdx.x < (unsigned)off) red[threadIdx.x] += red[threadIdx.x + off];
        __syncthreads();
    }
    const float scale = 32.0f * rsqrtf(red[0]);
    _Float16* dst = prev ? WpT : WcT;
#pragma unroll
    for (int s = 0; s < 4; ++s) {
        int i = threadIdx.x + s * 256;
        dst[(long)j * 1024 + i] = (_Float16)(K[(long)i * 1024 + j] * g[i] * scale);
    }
}

// ---------------------------------------------------------------------------
// Phase 2: Z = X @ Wc.  BM=256, BN=256, BK=64, 1024 threads (16 waves, 4x4
// wave grid, 64x64 tile per wave).  Per-block L2 traffic: A 1 MB + B 256 KB
// (vs old BM=64/BN=1024: 2 MB B per block = 4 GB aggregate -> L2-BW-bound).
// A staged fp32->f16 through XOR-swizzled LDS (flat stride 64 f16 would be a
// 32-way read conflict); X loads reg-double-buffered so the HBM stage hides
// under MFMA (1 block/CU -> no other wave-level overlap available).
// bid = rowgrp*4 + colgrp: the 4 col-blocks sharing a row-band dispatch
// adjacently -> X band HBM-fetched once, L3 serves the reuse.
// ---------------------------------------------------------------------------
__global__ __launch_bounds__(1024) void gemm_z(
    const float* __restrict__ X,        // [M][1024]
    const _Float16* __restrict__ WcT,   // [1024][1024]  (n-major)
    const float* __restrict__ bias,     // [1024]
    float* __restrict__ Z)              // [M][1024]  == d_out
{
    __shared__ _Float16 lA[256 * 64];   // 32 KB, rows XOR-swizzled

    const int tid  = threadIdx.x;
    const int wave = tid >> 6;          // 0..15
    const int lane = tid & 63;
    const int q    = lane >> 4;         // 0..3
    const int ln   = lane & 15;         // 0..15
    const int wr   = wave >> 2;         // 0..3  (row quadrant)
    const int wc   = wave & 3;          // 0..3  (col quadrant)
    const long m_base = (long)(blockIdx.x >> 2) * 256;
    const int  c_base = (blockIdx.x & 3) * 256 + wc * 64;

    const int srow  = tid >> 4;         // 0..63 (+p*64)
    const int sk    = (tid & 15) * 4;   // 0..60 (k elements)
    const int swz_w = (srow & 7) << 4;  // stage-write XOR (row&7 == srow&7)
    const int swz_r = (ln & 7) << 4;    // frag-read XOR  (row&7 == ln&7)

    floatx4 acc[4][4];
#pragma unroll
    for (int ms = 0; ms < 4; ++ms)
#pragma unroll
        for (int ns = 0; ns < 4; ++ns) acc[ms][ns] = (floatx4){0.f, 0.f, 0.f, 0.f};

    // prologue: prefetch k-tile 0 into registers
    float4 pf[4];
#pragma unroll
    for (int p = 0; p < 4; ++p)
        pf[p] = *(const float4*)(X + (m_base + srow + p * 64) * 1024 + sk);

    for (int k0 = 0; k0 < 1024; k0 += 64) {
        // write prefetched X tile (cvt fp32->f16) into swizzled LDS
#pragma unroll
        for (int p = 0; p < 4; ++p) {
            int r = srow + p * 64;
            half4v hv = { (_Float16)pf[p].x, (_Float16)pf[p].y,
                          (_Float16)pf[p].z, (_Float16)pf[p].w };
            *(half4v*)(&lA[r * 64 + (((sk * 2) ^ swz_w) >> 1)]) = hv;
        }
        __syncthreads();

        // prefetch next k-tile (overlaps with MFMA phase below)
        if (k0 < 960) {
#pragma unroll
            for (int p = 0; p < 4; ++p)
                pf[p] = *(const float4*)(X + (m_base + srow + p * 64) * 1024 + k0 + 64 + sk);
        }

#pragma unroll
        for (int kk = 0; kk < 2; ++kk) {
            half8 a[4];
#pragma unroll
            for (int ms = 0; ms < 4; ++ms) {
                int row = wr * 64 + ms * 16 + ln;
                a[ms] = *(const half8*)(&lA[row * 64 + (((kk * 64 + q * 16) ^ swz_r) >> 1)]);
            }
#pragma unroll
            for (int ns = 0; ns < 4; ++ns) {
                half8 b = *(const half8*)(WcT + (long)(c_base + ns * 16 + ln) * 1024
                                              + k0 + kk * 32 + q * 8);
#pragma unroll
                for (int ms = 0; ms < 4; ++ms)
                    acc[ms][ns] = __builtin_amdgcn_mfma_f32_16x16x32_f16(a[ms], b, acc[ms][ns], 0, 0, 0);
            }
        }
        __syncthreads();
    }

#pragma unroll
    for (int ns = 0; ns < 4; ++ns) {
        int col = c_base + ns * 16 + ln;
        float bs = bias[col];
#pragma unroll
        for (int ms = 0; ms < 4; ++ms) {
#pragma unroll
            for (int r = 0; r < 4; ++r) {
                long row = m_base + wr * 64 + ms * 16 + q * 4 + r;
                Z[row * 1024 + col] = acc[ms][ns][r] + bs;
            }
        }
    }
}

// ---------------------------------------------------------------------------
// Phase 3: cooperative 2-D recurrence, fence-free handshake (unchanged
// structure; verified).  This round: (a) hs XOR-swizzle (was ~8-way bank
// conflicted at stride 1032 -> 6.7e7 conflict cycles/dispatch); (b) the fp32
// Zout store moved AFTER the release signal so its write-ack is off the
// per-step critical chain.
// ---------------------------------------------------------------------------
__device__ __forceinline__ float fast_tanh(float x) {
    return 1.0f - 2.0f / (__expf(2.0f * x) + 1.0f);
}

__global__ __launch_bounds__(256, 1) void rnn_scan(
    const _Float16* __restrict__ WpT,   // [1024][1024] (n-major)
    float* __restrict__ Zout,           // [B][T][U], Z in, h out (in place)
    _Float16* __restrict__ hbuf,        // [2][256][1024] f16
    unsigned* __restrict__ cnt)         // [16][TN+1], pre-zeroed
{
    __shared__ _Float16 hs[16 * 1024];  // flat 32 KB, XOR-swizzled rows

    const int tid  = threadIdx.x;
    const int wave = tid >> 6;
    const int lane = tid & 63;
    const int q    = lane >> 4;         // 0..3
    const int ln   = lane & 15;         // 0..15
    const int bi   = blockIdx.x >> 4;   // batch group
    const int nj   = blockIdx.x & 15;   // col group
    const int ncol0 = nj * 64 + wave * 16;   // this wave's 16-col base
    const int hrow  = bi * 16 + ln;          // this lane's batch row
    const int swz_r = (ln & 7) << 4;

    unsigned* mycnt = cnt + bi * STEPS_P1;

    // ---- preload Wp slice into registers: cols [ncol0, ncol0+16) ----
    half8 b[32];
    {
        const _Float16* bp = WpT + (long)(ncol0 + ln) * 1024 + q * 8;
#pragma unroll
        for (int kk = 0; kk < 32; ++kk) b[kk] = *(const half8*)(bp + kk * 32);
    }

    // ---- init: zero own hbuf[0] slice (h_{-1}=0) via bypass stores ----
    {
        unsigned long long* p = (unsigned long long*)
            (hbuf + (long)(bi * 16 + (tid >> 4)) * 1024 + nj * 64 + (tid & 15) * 4);
        __hip_atomic_store(p, 0ull, __ATOMIC_RELAXED, __HIP_MEMORY_SCOPE_AGENT);
    }
    asm volatile("s_waitcnt vmcnt(0)" ::: "memory");
    __syncthreads();
    if (tid == 0)
        __hip_atomic_fetch_add(&mycnt[0], 1u, __ATOMIC_RELAXED, __HIP_MEMORY_SCOPE_AGENT);

    for (int t = 0; t < TN; ++t) {
        // ---- Z prefetch for this step (before the wait -> latency hidden) ----
        const long zoff = ((long)hrow * TN + t) * 1024 + ncol0 + q * 4;
        float4 z = *(const float4*)(Zout + zoff);

        // ---- wait: all 16 blocks of this group published h_{t-1} ----
        if (tid == 0) {
            while (__hip_atomic_load(&mycnt[t], __ATOMIC_RELAXED, __HIP_MEMORY_SCOPE_AGENT) < 16u)
                __builtin_amdgcn_s_sleep(1);
        }
        __syncthreads();
        __builtin_amdgcn_fence(__ATOMIC_ACQUIRE, "workgroup");  // compiler ordering; no cache inv

        // ---- stage h_{t-1} (32 KB) into swizzled LDS ----
        const unsigned long long* hp = (const unsigned long long*)
            (hbuf + (long)(t & 1) * (BN * UN) + (long)bi * 16 * 1024);
        unsigned long long tmp[16];
#pragma unroll
        for (int i = 0; i < 16; ++i)
            tmp[i] = __hip_atomic_load(hp + i * 256 + tid, __ATOMIC_RELAXED, __HIP_MEMORY_SCOPE_AGENT);
#pragma unroll
        for (int i = 0; i < 16; ++i) {
            int byte = (tid * 8) ^ ((i & 7) << 4);   // row i, 8B chunk tid
            *(unsigned long long*)(hs + i * 1024 + (byte >> 1)) = tmp[i];
        }
        __syncthreads();

        // ---- (Wp slice)^T x h : 32 k-iters, b from regs, a from LDS ----
        floatx4 acc[4];
#pragma unroll
        for (int c4 = 0; c4 < 4; ++c4) acc[c4] = (floatx4){0.f, 0.f, 0.f, 0.f};
#pragma unroll
        for (int kk = 0; kk < 32; ++kk) {
            half8 a = *(const half8*)(hs + ln * 1024 + (((kk * 64 + q * 16) ^ swz_r) >> 1));
            acc[kk & 3] = __builtin_amdgcn_mfma_f32_16x16x32_f16(b[kk], a, acc[kk & 3], 0, 0, 0);
        }
        floatx4 s = (acc[0] + acc[1]) + (acc[2] + acc[3]);

        // ---- epilogue: tanh, publish h (critical), signal, THEN Z write ----
        float4 hv;
        hv.x = fast_tanh(z.x + s[0]);
        hv.y = fast_tanh(z.y + s[1]);
        hv.z = fast_tanh(z.z + s[2]);
        hv.w = fast_tanh(z.w + s[3]);

        union { _Float16 h[4]; unsigned long long u; } pk;
        pk.h[0] = (_Float16)hv.x; pk.h[1] = (_Float16)hv.y;
        pk.h[2] = (_Float16)hv.z; pk.h[3] = (_Float16)hv.w;
        unsigned long long* hn = (unsigned long long*)
            (hbuf + (long)((t + 1) & 1) * (BN * UN) + (long)hrow * 1024 + ncol0 + q * 4);
        __hip_atomic_store(hn, pk.u, __ATOMIC_RELAXED, __HIP_MEMORY_SCOPE_AGENT);

        // release: own h store acked at coherence point, then signal
        asm volatile("s_waitcnt vmcnt(0)" ::: "memory");
        __syncthreads();
        if (tid == 0)
            __hip_atomic_fetch_add(&mycnt[t + 1], 1u, __ATOMIC_RELAXED, __HIP_MEMORY_SCOPE_AGENT);

        // fire-and-forget fp32 output write (off the handshake chain)
        *(float4*)(Zout + zoff) = hv;
    }
}

// ---------------------------------------------------------------------------
extern "C" void kernel_launch(void* const* d_in, const int* in_sizes, int n_in,
                              void* d_out, int out_size, void* d_ws, size_t ws_size,
                              hipStream_t stream) {
    (void)in_sizes; (void)n_in; (void)out_size; (void)ws_size;
    const float* X    = (const float*)d_in[0];
    // d_in[1] = h0 (zeros, folded into hbuf init)
    const float* K    = (const float*)d_in[2];
    const float* RK   = (const float*)d_in[3];
    const float* bias = (const float*)d_in[4];
    const float* muc  = (const float*)d_in[5];
    const float* sic  = (const float*)d_in[6];
    const float* mup  = (const float*)d_in[7];
    const float* sip  = (const float*)d_in[8];
    float* out = (float*)d_out;

    // Workspace layout (4 MiB):
    //   [0, 2 MiB)   WcT  (dead after gemm_z) — reused by rnn_scan as:
    //                [0, 1 MiB)        hbuf  (2 x 256 x 1024 f16)
    //                [1 MiB, +32.1 KB) barrier counters
    //   [2 MiB, 4 MiB) WpT
    _Float16* WcT  = (_Float16*)d_ws;
    _Float16* WpT  = WcT + 1024 * 1024;
    _Float16* hbuf = (_Float16*)d_ws;
    unsigned* cnt  = (unsigned*)((char*)d_ws + (1u << 20));

    prep_weights<<<dim3(1024, 2), 256, 0, stream>>>(K, RK, muc, sic, mup, sip, WcT, WpT);
    gemm_z<<<dim3((BN * TN / 256) * 4), 1024, 0, stream>>>(X, WcT, bias, out);

    // zero the per-step barrier counters (after gemm_z — region aliases WcT)
    hipMemsetAsync(cnt, 0, 16 * STEPS_P1 * sizeof(unsigned), stream);

    const _Float16* WpT_c = WpT;
    float* out_p = out;
    _Float16* hbuf_p = hbuf;
    unsigned* cnt_p = cnt;
    void* kargs[] = { (void*)&WpT_c, (void*)&out_p, (void*)&hbuf_p, (void*)&cnt_p };
    hipLaunchCooperativeKernel((const void*)rnn_scan, dim3(16 * 16), dim3(256),
                               kargs, 0, stream);
}